// Round 2
// baseline (675.224 us; speedup 1.0000x reference)
//
#include <hip/hip_runtime.h>
#include <math.h>

#define T_TOK 32768
#define D_DIM 128
#define K_CODE 8192
#define BM 512              // tokens per step (argmin): 4 waves x 128
#define BN 64               // codes per block (argmin)
#define NTOK 8              // token steps per block (4096 tokens/block)

typedef unsigned long long ull;
typedef _Float16 v8h __attribute__((ext_vector_type(8)));
typedef _Float16 v4h __attribute__((ext_vector_type(4)));
typedef float v16f __attribute__((ext_vector_type(16)));

#define SCALE 4096.0f        // 2^12: pushes f16 split residuals into normal range
#define DESCALE (1.0f / 4096.0f)
#define ACC_SCALE (-0x1p-23f)   // s = (zn+cn) - 2*dot, dot = acc*2^-24

// Cpack layout (bytes): [cb=code/64][ (s*2+mt)*8+kc ][lane64][j8 f16]
// Zpack layout (bytes): [tb=token/32][ s ][ kc ][lane64][j8 f16]

// ---------------- proj: codebook row -> f16 split packs + cn ----------------
// 256-thread blocks, 4 rows/block (1 wave per row, arithmetic identical to the
// 64-thread version); 4x W reuse through L1, 4x fewer dispatch packets.
__global__ __launch_bounds__(256) void proj_kernel(const float* __restrict__ E,
                                                  const float* __restrict__ W,
                                                  const float* __restrict__ b,
                                                  char* __restrict__ Cpack,
                                                  float* __restrict__ cn) {
    int r = blockIdx.x * 4 + (threadIdx.x >> 6);
    int l = threadIdx.x & 63;          // 0..63
    const float4* E4 = (const float4*)(E + (size_t)r * D_DIM);
    const float4* WA = (const float4*)(W + (size_t)l * D_DIM);
    const float4* WB = (const float4*)(W + (size_t)(l + 64) * D_DIM);

    float4 aA = make_float4(0.f, 0.f, 0.f, 0.f);
    float4 aB = make_float4(0.f, 0.f, 0.f, 0.f);
#pragma unroll
    for (int dd = 0; dd < 32; ++dd) {
        float4 e = E4[dd];
        float4 wa = WA[dd], wb = WB[dd];
        aA.x = fmaf(e.x, wa.x, aA.x);
        aA.y = fmaf(e.y, wa.y, aA.y);
        aA.z = fmaf(e.z, wa.z, aA.z);
        aA.w = fmaf(e.w, wa.w, aA.w);
        aB.x = fmaf(e.x, wb.x, aB.x);
        aB.y = fmaf(e.y, wb.y, aB.y);
        aB.z = fmaf(e.z, wb.z, aB.z);
        aB.w = fmaf(e.w, wb.w, aB.w);
    }
    float vA = ((aA.x + aA.y) + (aA.z + aA.w)) + b[l];
    float vB = ((aB.x + aB.y) + (aB.z + aB.w)) + b[l + 64];

    char* cp = Cpack + (size_t)(r >> 6) * 32768;
    int mt = (r >> 5) & 1, rs = r & 31;
    {   // d = l
        int kc = l >> 4, hf = (l >> 3) & 1, j = l & 7;
        float f = vA * SCALE;
        _Float16 h = (_Float16)f;
        _Float16 m = (_Float16)(f - (float)h);
        size_t off = (size_t)((mt * 8 + kc) * 1024 + (hf * 32 + rs) * 16 + j * 2);
        *(_Float16*)(cp + off) = h;
        *(_Float16*)(cp + off + 16384) = m;
    }
    {   // d = l + 64
        int d = l + 64;
        int kc = d >> 4, hf = (d >> 3) & 1, j = d & 7;
        float f = vB * SCALE;
        _Float16 h = (_Float16)f;
        _Float16 m = (_Float16)(f - (float)h);
        size_t off = (size_t)((mt * 8 + kc) * 1024 + (hf * 32 + rs) * 16 + j * 2);
        *(_Float16*)(cp + off) = h;
        *(_Float16*)(cp + off + 16384) = m;
    }

    float s = vA * vA + vB * vB;
#pragma unroll
    for (int off = 32; off > 0; off >>= 1) s += __shfl_down(s, off, 64);
    if (l == 0) cn[r] = s;
}

// ---------------- znorm (bit-identical per-wave reduce) + fused inits -------
__global__ __launch_bounds__(256) void znorm_kernel(const float* __restrict__ Z,
                                                   float* __restrict__ zn,
                                                   ull* __restrict__ packed,
                                                   int* __restrict__ counts) {
    int t = blockIdx.x * 4 + (threadIdx.x >> 6);
    int l = threadIdx.x & 63;
    float a = Z[(size_t)t * D_DIM + l];
    float b2 = Z[(size_t)t * D_DIM + 64 + l];
    float s = a * a + b2 * b2;
#pragma unroll
    for (int off = 32; off > 0; off >>= 1) s += __shfl_down(s, off, 64);
    if (l == 0) {
        zn[t] = s;
        packed[t] = ~0ull;
        if (t < K_CODE) counts[t] = 0;
    }
}

// ---------------- prep_z: z -> f16 split packs (B-fragment layout) ----------
__global__ __launch_bounds__(256) void prep_z_kernel(const float* __restrict__ Z,
                                                     char* __restrict__ Zpack) {
    int tb = blockIdx.x;          // 32-token group
    int tid = threadIdx.x;
    int lane = tid & 63;
    int w = tid >> 6;
    char* zp = Zpack + (size_t)tb * 16384;
#pragma unroll
    for (int kq = 0; kq < 2; ++kq) {
        int kc = 2 * w + kq;
        const float* src = Z + (size_t)(tb * 32 + (lane & 31)) * D_DIM
                             + kc * 16 + (lane >> 5) * 8;
        float4 a = *(const float4*)(src);
        float4 c = *(const float4*)(src + 4);
        float vals[8] = {a.x, a.y, a.z, a.w, c.x, c.y, c.z, c.w};
        v8h h, m;
#pragma unroll
        for (int j = 0; j < 8; ++j) {
            float f = vals[j] * SCALE;
            _Float16 hh = (_Float16)f;
            h[j] = hh;
            m[j] = (_Float16)(f - (float)hh);
        }
        *(v8h*)(zp + (size_t)(kc * 1024 + lane * 16)) = h;
        *(v8h*)(zp + (size_t)(8192 + kc * 1024 + lane * 16)) = m;
    }
}

// ---------------- async Cpack stage: global -> LDS (linear, 16B) ------------
__device__ __forceinline__ void stage_tile(char* ldsdst, const char* gsrc,
                                           int w, int lane) {
#pragma unroll
    for (int it = 0; it < 8; ++it) {
        int off = (w * 8 + it) * 1024;
        __builtin_amdgcn_global_load_lds(
            (const __attribute__((address_space(1))) void*)(gsrc + off + lane * 16),
            (__attribute__((address_space(3))) void*)(ldsdst + off),
            16, 0, 0);
    }
}

// ---------------- MFMA argmin: token-persistent, code tile staged once ------
// R11 post-mortem: code-persistence thrashed L2 (FETCH 68->923 MB: resident
// blocks spanned 32 Zpack slices x 8 re-reads vs 4 MB/XCD L2). Flip the axis:
// block owns ONE 64-code LDS tile (staged once -> single barrier, zero race
// surface, staging cost /8) and sweeps 8 token-steps. Grid (128,8) x-fastest
// keeps resident blocks on 4 co-swept token windows -> Zpack L2-hot. No
// barriers in the loop: 8 free-running waves/CU overlap epilogue with MFMA.
// Per-(token,code) arithmetic and tie-breaking identical to the exact R0 path.
__global__ __launch_bounds__(256, 2) void argmin_kernel(const char* __restrict__ Zpack,
                                                        const char* __restrict__ Cpack,
                                                        const float* __restrict__ cn,
                                                        const float* __restrict__ zn,
                                                        ull* __restrict__ packed) {
    __shared__ __align__(16) char lds[33024];   // 32768 A-pack + 256 cn

    int tid = threadIdx.x;
    int lane = tid & 63;
    int w = __builtin_amdgcn_readfirstlane(tid >> 6);
    int half_id = lane >> 5;
    int cb = blockIdx.x;          // code block (64 codes) — owned for all steps
    int nb = cb * BN;

    // one-time stage: Cpack chunk (async, 16B) + cn slice
    stage_tile(lds, Cpack + (size_t)cb * 32768, w, lane);
    if (tid < 64) ((float*)(lds + 32768))[tid] = cn[nb + tid];

    int mb0 = blockIdx.y * (NTOK * BM);
    const char* zb_first = Zpack + ((size_t)(mb0 >> 5) + 4 * w) * 16384 + lane * 16;

    // initial B prefetch (kc=0,1 of step 0); steps hand it forward
    v8h pb[8][2];
#pragma unroll
    for (int n = 0; n < 4; ++n) {
        pb[2 * n + 0][0] = *(const v8h*)(zb_first + n * 16384);
        pb[2 * n + 1][0] = *(const v8h*)(zb_first + n * 16384 + 8192);
        pb[2 * n + 0][1] = *(const v8h*)(zb_first + n * 16384 + 1024);
        pb[2 * n + 1][1] = *(const v8h*)(zb_first + n * 16384 + 8192 + 1024);
    }

    __syncthreads();   // drains staging; LDS is read-only from here on

    const char* ab = lds + lane * 16;
    const float* cn_s = (const float*)(lds + 32768);

#pragma unroll 1
    for (int tt = 0; tt < NTOK; ++tt) {
        int mb = mb0 + tt * BM;
        const char* zb0 = Zpack + ((size_t)(mb >> 5) + 4 * w) * 16384 + lane * 16;
        // next step's slice base; clamped at the last step (stays in-bounds)
        const char* zbn = (tt + 1 < NTOK) ? (zb0 + BM * 512) : zb0;

        // per-token |z|^2 for this step — issued early, consumed in epilogue
        float znv[4];
#pragma unroll
        for (int n = 0; n < 4; ++n) znv[n] = zn[mb + w * 128 + n * 32 + (lane & 31)];

        v16f acc[2][4];               // [mt codes][n token-groups]
#pragma unroll
        for (int mt = 0; mt < 2; ++mt)
#pragma unroll
            for (int n = 0; n < 4; ++n) acc[mt][n] = (v16f)0.f;

#pragma unroll
        for (int kc = 0; kc < 8; ++kc) {
            int curb = kc & 1;
            v8h Bh[4], Bm[4];
#pragma unroll
            for (int n = 0; n < 4; ++n) { Bh[n] = pb[2 * n][curb]; Bm[n] = pb[2 * n + 1][curb]; }
            {   // refill with (kc+2)&7; kc=6,7 pull kc=0,1 of the NEXT step
                const char* rb = (kc < 6) ? zb0 : zbn;   // compile-time per kc
                int knx = (kc + 2) & 7;
#pragma unroll
                for (int n = 0; n < 4; ++n) {
                    pb[2 * n + 0][curb] = *(const v8h*)(rb + n * 16384 + knx * 1024);
                    pb[2 * n + 1][curb] = *(const v8h*)(rb + n * 16384 + 8192 + knx * 1024);
                }
            }
            v8h Ah0 = *(const v8h*)(ab + (0 * 8 + kc) * 1024);       // mt0 hi
            v8h Ah1 = *(const v8h*)(ab + (1 * 8 + kc) * 1024);       // mt1 hi
            v8h Am0 = *(const v8h*)(ab + (2 * 8 + kc) * 1024);       // mt0 lo
            v8h Am1 = *(const v8h*)(ab + (3 * 8 + kc) * 1024);       // mt1 lo

            // pass h*h (same-acc distance = 8)
#pragma unroll
            for (int n = 0; n < 4; ++n)
                acc[0][n] = __builtin_amdgcn_mfma_f32_32x32x16_f16(Ah0, Bh[n], acc[0][n], 0, 0, 0);
#pragma unroll
            for (int n = 0; n < 4; ++n)
                acc[1][n] = __builtin_amdgcn_mfma_f32_32x32x16_f16(Ah1, Bh[n], acc[1][n], 0, 0, 0);
            // pass h*m
#pragma unroll
            for (int n = 0; n < 4; ++n)
                acc[0][n] = __builtin_amdgcn_mfma_f32_32x32x16_f16(Ah0, Bm[n], acc[0][n], 0, 0, 0);
#pragma unroll
            for (int n = 0; n < 4; ++n)
                acc[1][n] = __builtin_amdgcn_mfma_f32_32x32x16_f16(Ah1, Bm[n], acc[1][n], 0, 0, 0);
            // pass m*h
#pragma unroll
            for (int n = 0; n < 4; ++n)
                acc[0][n] = __builtin_amdgcn_mfma_f32_32x32x16_f16(Am0, Bh[n], acc[0][n], 0, 0, 0);
#pragma unroll
            for (int n = 0; n < 4; ++n)
                acc[1][n] = __builtin_amdgcn_mfma_f32_32x32x16_f16(Am1, Bh[n], acc[1][n], 0, 0, 0);
        }

        // ---- epilogue (exact R0 arithmetic): per-step argmin + atomics ----
        float best[4];
        int bi[4];
#pragma unroll
        for (int n = 0; n < 4; ++n) { best[n] = 3.4e38f; bi[n] = nb; }

#pragma unroll
        for (int mt = 0; mt < 2; ++mt) {
            float cnreg[16];
#pragma unroll
            for (int reg = 0; reg < 16; ++reg) {
                int mrow = 32 * mt + (reg & 3) + 8 * (reg >> 2) + 4 * half_id;
                cnreg[reg] = cn_s[mrow];
            }
#pragma unroll
            for (int n = 0; n < 4; ++n) {
#pragma unroll
                for (int reg = 0; reg < 16; ++reg) {
                    // ascending code order within half -> strict < keeps first-min
                    int mrow = 32 * mt + (reg & 3) + 8 * (reg >> 2) + 4 * half_id;
                    int code = nb + mrow;
                    // s = (zn + cn) - 2*dot ; dot = acc*2^-24 (exact scale), fused
                    float s = fmaf(acc[mt][n][reg], ACC_SCALE, znv[n] + cnreg[reg]);
                    if (s < best[n]) { best[n] = s; bi[n] = code; }
                }
            }
        }

        // cross-half combine with explicit smaller-idx tie-break
#pragma unroll
        for (int n = 0; n < 4; ++n) {
            float ob = __shfl_xor(best[n], 32, 64);
            int oi = __shfl_xor(bi[n], 32, 64);
            if (ob < best[n] || (ob == best[n] && oi < bi[n])) { best[n] = ob; bi[n] = oi; }
            // d > 0 -> f32 bits monotone as uint; idx in low bits -> first-min ties
            if ((n >> 1) == half_id) {
                int tok = mb + w * 128 + n * 32 + (lane & 31);
                ull pk = ((ull)__float_as_uint(best[n]) << 32) | (unsigned)bi[n];
                atomicMin(&packed[tok], pk);
            }
        }
    }
}

// ---------------- zq: unpack winner, reconstruct code row, out + counts + loss
__global__ __launch_bounds__(256) void zq_kernel(const float* __restrict__ Z,
                                                 const char* __restrict__ Cpack,
                                                 const ull* __restrict__ packed,
                                                 float* __restrict__ out,
                                                 int* __restrict__ counts,
                                                 float* __restrict__ lpart) {
    int gid = blockIdx.x * 256 + threadIdx.x;   // over T*D/4 float4s
    int t = gid >> 5;                           // 32 float4 per token
    int d4 = gid & 31;
    int idx = (int)(packed[t] & 0xFFFFFFFFull);
    if (d4 == 0) atomicAdd(&counts[idx], 1);

    // reconstruct c[d0..d0+3] = (ch + cm) * 2^-12 (exact sum: spans < 24 bits)
    int d0 = 4 * d4;
    int kc = d0 >> 4, hf = (d0 >> 3) & 1, j0 = d0 & 7;
    const char* cp = Cpack + (size_t)(idx >> 6) * 32768
                   + (size_t)((((idx >> 5) & 1) * 8 + kc) * 1024
                              + (hf * 32 + (idx & 31)) * 16 + j0 * 2);
    v4h h = *(const v4h*)(cp);
    v4h m = *(const v4h*)(cp + 16384);
    float4 cv;
    cv.x = ((float)h[0] + (float)m[0]) * DESCALE;
    cv.y = ((float)h[1] + (float)m[1]) * DESCALE;
    cv.z = ((float)h[2] + (float)m[2]) * DESCALE;
    cv.w = ((float)h[3] + (float)m[3]) * DESCALE;

    float4 zv = ((const float4*)Z)[gid];
    float dx = cv.x - zv.x, dy = cv.y - zv.y, dz = cv.z - zv.z, dw = cv.w - zv.w;
    float4 o;
    o.x = zv.x + dx;    // z + (z_q - z): match reference elementwise rounding
    o.y = zv.y + dy;
    o.z = zv.z + dz;
    o.w = zv.w + dw;
    ((float4*)out)[gid] = o;

    float ls = dx * dx + dy * dy + dz * dz + dw * dw;
#pragma unroll
    for (int off = 32; off > 0; off >>= 1) ls += __shfl_down(ls, off, 64);
    __shared__ float red[4];
    int lane = threadIdx.x & 63, w = threadIdx.x >> 6;
    if (lane == 0) red[w] = ls;
    __syncthreads();
    // per-block partial store: no same-address atomic serialization
    if (threadIdx.x == 0) lpart[blockIdx.x] = (red[0] + red[1]) + (red[2] + red[3]);
}

// ---------------- scalars: commit_loss (from partials), perplexity ----------
__global__ __launch_bounds__(256) void scalars_kernel(const int* __restrict__ counts,
                                                      const float* __restrict__ lpart,
                                                      float* __restrict__ out) {
    float s = 0.f;
    for (int i = threadIdx.x; i < K_CODE; i += 256) {
        float e = (float)counts[i] * (1.0f / (float)T_TOK);
        s += e * logf(e + 1e-8f);
    }
    float ls = 0.f;
    for (int i = threadIdx.x; i < 4096; i += 256) ls += lpart[i];
#pragma unroll
    for (int off = 32; off > 0; off >>= 1) {
        s += __shfl_down(s, off, 64);
        ls += __shfl_down(ls, off, 64);
    }
    __shared__ float red[8];
    int lane = threadIdx.x & 63, w = threadIdx.x >> 6;
    if (lane == 0) { red[w] = s; red[4 + w] = ls; }
    __syncthreads();
    if (threadIdx.x == 0) {
        float ssum = (red[0] + red[1]) + (red[2] + red[3]);
        float lsum = (red[4] + red[5]) + (red[6] + red[7]);
        out[(size_t)T_TOK * D_DIM + 0] = 1.25f * lsum / (float)((size_t)T_TOK * D_DIM);
        out[(size_t)T_TOK * D_DIM + 1] = expf(-ssum);
    }
}

extern "C" void kernel_launch(void* const* d_in, const int* in_sizes, int n_in,
                              void* d_out, int out_size, void* d_ws, size_t ws_size,
                              hipStream_t stream) {
    const float* z   = (const float*)d_in[0];   // [8,4096,128]
    const float* emb = (const float*)d_in[1];   // [8192,128]
    const float* pw  = (const float*)d_in[2];   // [128,128]
    const float* pb  = (const float*)d_in[3];   // [128]
    float* out = (float*)d_out;

    // Zpack (f16 split fragments, 16.78 MB) lives in d_out: dead scratch until
    // zq_kernel overwrites d_out with the final z_q_st.
    char* Zpack = (char*)d_out;

    char* ws = (char*)d_ws;
    // layout (bytes):
    //   Cpack:  0        .. 4194304   (128 cb x 32768)
    //   cn:     4194304  .. 4227072   (8192 f32)
    //   zn:     4227072  .. 4358144   (32768 f32)  [lpart aliases this after argmin]
    //   packed: 4358144  .. 4620288   (32768 u64)
    //   counts: 4620288  .. 4653056   (8192 i32)
    char*  Cpack  = ws + 0;
    float* cn     = (float*)(ws + 4194304);
    float* zn     = (float*)(ws + 4227072);
    ull*   packed = (ull*)  (ws + 4358144);
    int*   counts = (int*)  (ws + 4620288);
    float* lpart  = (float*)(ws + 4227072);    // zn region is dead after argmin

    proj_kernel<<<K_CODE / 4, 256, 0, stream>>>(emb, pw, pb, Cpack, cn);
    prep_z_kernel<<<T_TOK / 32, 256, 0, stream>>>(z, Zpack);
    znorm_kernel<<<T_TOK / 4, 256, 0, stream>>>(z, zn, packed, counts);
    argmin_kernel<<<dim3(K_CODE / BN, T_TOK / (NTOK * BM)), 256, 0, stream>>>(Zpack, Cpack, cn, zn, packed);
    zq_kernel<<<(T_TOK * D_DIM / 4) / 256, 256, 0, stream>>>(z, Cpack, packed, out, counts, lpart);
    scalars_kernel<<<1, 256, 0, stream>>>(counts, lpart, out);
}

// Round 3
// 375.940 us; speedup vs baseline: 1.7961x; 1.7961x over previous
//
#include <hip/hip_runtime.h>
#include <math.h>

#define T_TOK 32768
#define D_DIM 128
#define K_CODE 8192
#define BM 1024             // tokens per block (argmin): 8 waves x 128
#define BN 64               // codes per block (argmin)

typedef unsigned long long ull;
typedef _Float16 v8h __attribute__((ext_vector_type(8)));
typedef _Float16 v4h __attribute__((ext_vector_type(4)));
typedef float v16f __attribute__((ext_vector_type(16)));

#define SCALE 4096.0f        // 2^12: pushes f16 split residuals into normal range
#define DESCALE (1.0f / 4096.0f)
#define ACC_SCALE (-0x1p-23f)   // s' = cn - 2*dot (zn dropped: token-constant)

// Cpack layout (bytes): [cb=code/64][ (s*2+mt)*8+kc ][lane64][j8 f16]
// Zpack layout (bytes): [tb=token/32][ s ][ kc ][lane64][j8 f16]

// ---------------- proj: codebook row -> f16 split packs + cn ----------------
__global__ __launch_bounds__(256) void proj_kernel(const float* __restrict__ E,
                                                  const float* __restrict__ W,
                                                  const float* __restrict__ b,
                                                  char* __restrict__ Cpack,
                                                  float* __restrict__ cn) {
    int r = blockIdx.x * 4 + (threadIdx.x >> 6);
    int l = threadIdx.x & 63;          // 0..63
    const float4* E4 = (const float4*)(E + (size_t)r * D_DIM);
    const float4* WA = (const float4*)(W + (size_t)l * D_DIM);
    const float4* WB = (const float4*)(W + (size_t)(l + 64) * D_DIM);

    float4 aA = make_float4(0.f, 0.f, 0.f, 0.f);
    float4 aB = make_float4(0.f, 0.f, 0.f, 0.f);
#pragma unroll
    for (int dd = 0; dd < 32; ++dd) {
        float4 e = E4[dd];
        float4 wa = WA[dd], wb = WB[dd];
        aA.x = fmaf(e.x, wa.x, aA.x);
        aA.y = fmaf(e.y, wa.y, aA.y);
        aA.z = fmaf(e.z, wa.z, aA.z);
        aA.w = fmaf(e.w, wa.w, aA.w);
        aB.x = fmaf(e.x, wb.x, aB.x);
        aB.y = fmaf(e.y, wb.y, aB.y);
        aB.z = fmaf(e.z, wb.z, aB.z);
        aB.w = fmaf(e.w, wb.w, aB.w);
    }
    float vA = ((aA.x + aA.y) + (aA.z + aA.w)) + b[l];
    float vB = ((aB.x + aB.y) + (aB.z + aB.w)) + b[l + 64];

    char* cp = Cpack + (size_t)(r >> 6) * 32768;
    int mt = (r >> 5) & 1, rs = r & 31;
    {   // d = l
        int kc = l >> 4, hf = (l >> 3) & 1, j = l & 7;
        float f = vA * SCALE;
        _Float16 h = (_Float16)f;
        _Float16 m = (_Float16)(f - (float)h);
        size_t off = (size_t)((mt * 8 + kc) * 1024 + (hf * 32 + rs) * 16 + j * 2);
        *(_Float16*)(cp + off) = h;
        *(_Float16*)(cp + off + 16384) = m;
    }
    {   // d = l + 64
        int d = l + 64;
        int kc = d >> 4, hf = (d >> 3) & 1, j = d & 7;
        float f = vB * SCALE;
        _Float16 h = (_Float16)f;
        _Float16 m = (_Float16)(f - (float)h);
        size_t off = (size_t)((mt * 8 + kc) * 1024 + (hf * 32 + rs) * 16 + j * 2);
        *(_Float16*)(cp + off) = h;
        *(_Float16*)(cp + off + 16384) = m;
    }

    float s = vA * vA + vB * vB;
#pragma unroll
    for (int off = 32; off > 0; off >>= 1) s += __shfl_down(s, off, 64);
    if (l == 0) cn[r] = s;
}

// ---------------- prep_z: z -> f16 split packs + fused inits ----------------
__global__ __launch_bounds__(256) void prep_z_kernel(const float* __restrict__ Z,
                                                     char* __restrict__ Zpack,
                                                     ull* __restrict__ packed,
                                                     int* __restrict__ counts) {
    int tb = blockIdx.x;          // 32-token group
    int tid = threadIdx.x;
    int lane = tid & 63;
    int w = tid >> 6;

    // fused inits (zn kernel removed entirely: argmin no longer needs |z|^2)
    int g = blockIdx.x * 256 + tid;
    if (g < T_TOK) packed[g] = ~0ull;
    if (g < K_CODE) counts[g] = 0;

    char* zp = Zpack + (size_t)tb * 16384;
#pragma unroll
    for (int kq = 0; kq < 2; ++kq) {
        int kc = 2 * w + kq;
        const float* src = Z + (size_t)(tb * 32 + (lane & 31)) * D_DIM
                             + kc * 16 + (lane >> 5) * 8;
        float4 a = *(const float4*)(src);
        float4 c = *(const float4*)(src + 4);
        float vals[8] = {a.x, a.y, a.z, a.w, c.x, c.y, c.z, c.w};
        v8h h, m;
#pragma unroll
        for (int j = 0; j < 8; ++j) {
            float f = vals[j] * SCALE;
            _Float16 hh = (_Float16)f;
            h[j] = hh;
            m[j] = (_Float16)(f - (float)hh);
        }
        *(v8h*)(zp + (size_t)(kc * 1024 + lane * 16)) = h;
        *(v8h*)(zp + (size_t)(8192 + kc * 1024 + lane * 16)) = m;
    }
}

// ---------------- MFMA argmin: 8-wave block, XCD-swizzled, zn-free ----------
// R12 post-mortem: ANY persistence (code- or token-axis) blows the per-XCD L2
// working set -> Zpack re-reads go to HBM (757-923 MB FETCH). Back to the
// exact R0 inner loop; fix the schedule instead:
//  - 512-thread block = 8 waves sharing ONE 32 KB A-tile stage + ONE barrier
//    per 1024 tokens (R0 paid 2 stages+barriers and the two resident blocks
//    were dispatch-phase-locked -> matrix pipe drained at each epilogue).
//  - XCD swizzle: all 128 cb-blocks of a token window on one XCD -> the
//    window's 512 KB Zpack slice is fetched once, B-refills run at L2 rate
//    (64 KB/layer ~ 1.1k cyc < 1.55k cyc matrix), packed[] atomics XCD-local.
//  - zn dropped from the scan (token-constant, cancels in every comparison);
//    cross-block key uses the monotone float-bits encode (s' may be < 0).
__global__ __launch_bounds__(512, 2) void argmin_kernel(const char* __restrict__ Zpack,
                                                        const char* __restrict__ Cpack,
                                                        const float* __restrict__ cn,
                                                        ull* __restrict__ packed) {
    __shared__ __align__(16) char lds[33024];   // 32768 A-pack + 256 cn

    int tid = threadIdx.x;
    int lane = tid & 63;
    int w = __builtin_amdgcn_readfirstlane(tid >> 6);   // 0..7
    int half_id = lane >> 5;

    // XCD swizzle (bijective over 4096): bid%8 selects the XCD on MI355X.
    // win = (bid&7) + 8*(bid>>10): the 128 cb-blocks of window `win` are all
    // congruent mod 8 -> co-located on one XCD, consecutive in dispatch.
    int bid = blockIdx.y * 128 + blockIdx.x;
    int q = bid >> 3;
    int cb = q & 127;                  // code block (64 codes)
    int win = (bid & 7) + 8 * (q >> 7);
    int nb = cb * BN;
    int mb = win * BM;                 // token window (1024 tokens)

    // ---- one-time stage: A-pack via async global_load_lds (16B, linear) ----
    {
        const char* src = Cpack + (size_t)cb * 32768;
#pragma unroll
        for (int it = 0; it < 4; ++it) {
            int off = it * 8192 + tid * 16;
            __builtin_amdgcn_global_load_lds(
                (const __attribute__((address_space(1))) void*)(src + off),
                (__attribute__((address_space(3))) void*)(lds + off),
                16, 0, 0);
        }
        if (tid < 64) ((float*)(lds + 32768))[tid] = cn[nb + tid];
    }

    int tbw = (mb >> 5) + 4 * w;       // wave w owns token groups tbw..tbw+3
    const char* zb0 = Zpack + (size_t)tbw * 16384 + lane * 16;

    // 2-deep register prefetch: pb[frag = n*2 + split][buf = kc&1]
    v8h pb[8][2];
#pragma unroll
    for (int n = 0; n < 4; ++n) {
        pb[2 * n + 0][0] = *(const v8h*)(zb0 + n * 16384);
        pb[2 * n + 1][0] = *(const v8h*)(zb0 + n * 16384 + 8192);
        pb[2 * n + 0][1] = *(const v8h*)(zb0 + n * 16384 + 1024);
        pb[2 * n + 1][1] = *(const v8h*)(zb0 + n * 16384 + 8192 + 1024);
    }

    __syncthreads();   // drains staging; LDS read-only after this

    const char* ab = lds + lane * 16;
    const float* cn_s = (const float*)(lds + 32768);

    v16f acc[2][4];               // [mt codes][n token-groups]
#pragma unroll
    for (int mt = 0; mt < 2; ++mt)
#pragma unroll
        for (int n = 0; n < 4; ++n) acc[mt][n] = (v16f)0.f;

#pragma unroll
    for (int kc = 0; kc < 8; ++kc) {
        int curb = kc & 1;
        v8h Bh[4], Bm[4];
#pragma unroll
        for (int n = 0; n < 4; ++n) { Bh[n] = pb[2 * n][curb]; Bm[n] = pb[2 * n + 1][curb]; }
        if (kc < 6) {   // refill this buffer with kc+2 before the MFMAs
#pragma unroll
            for (int n = 0; n < 4; ++n) {
                pb[2 * n + 0][curb] = *(const v8h*)(zb0 + n * 16384 + (kc + 2) * 1024);
                pb[2 * n + 1][curb] = *(const v8h*)(zb0 + n * 16384 + 8192 + (kc + 2) * 1024);
            }
        }
        v8h Ah0 = *(const v8h*)(ab + (0 * 8 + kc) * 1024);       // mt0 hi
        v8h Ah1 = *(const v8h*)(ab + (1 * 8 + kc) * 1024);       // mt1 hi
        v8h Am0 = *(const v8h*)(ab + (2 * 8 + kc) * 1024);       // mt0 lo
        v8h Am1 = *(const v8h*)(ab + (3 * 8 + kc) * 1024);       // mt1 lo

        // pass h*h (same-acc distance = 8)
#pragma unroll
        for (int n = 0; n < 4; ++n)
            acc[0][n] = __builtin_amdgcn_mfma_f32_32x32x16_f16(Ah0, Bh[n], acc[0][n], 0, 0, 0);
#pragma unroll
        for (int n = 0; n < 4; ++n)
            acc[1][n] = __builtin_amdgcn_mfma_f32_32x32x16_f16(Ah1, Bh[n], acc[1][n], 0, 0, 0);
        // pass h*m
#pragma unroll
        for (int n = 0; n < 4; ++n)
            acc[0][n] = __builtin_amdgcn_mfma_f32_32x32x16_f16(Ah0, Bm[n], acc[0][n], 0, 0, 0);
#pragma unroll
        for (int n = 0; n < 4; ++n)
            acc[1][n] = __builtin_amdgcn_mfma_f32_32x32x16_f16(Ah1, Bm[n], acc[1][n], 0, 0, 0);
        // pass m*h
#pragma unroll
        for (int n = 0; n < 4; ++n)
            acc[0][n] = __builtin_amdgcn_mfma_f32_32x32x16_f16(Am0, Bh[n], acc[0][n], 0, 0, 0);
#pragma unroll
        for (int n = 0; n < 4; ++n)
            acc[1][n] = __builtin_amdgcn_mfma_f32_32x32x16_f16(Am1, Bh[n], acc[1][n], 0, 0, 0);
    }

    // ---- epilogue: in-lane argmin per token group (zn-free: s' = cn - 2dot,
    // token-constant zn cancels in every comparison) ----
    float best[4];
    int bi[4];
#pragma unroll
    for (int n = 0; n < 4; ++n) { best[n] = 3.4e38f; bi[n] = nb; }

#pragma unroll
    for (int mt = 0; mt < 2; ++mt) {
        float cnreg[16];
#pragma unroll
        for (int reg = 0; reg < 16; ++reg) {
            int mrow = 32 * mt + (reg & 3) + 8 * (reg >> 2) + 4 * half_id;
            cnreg[reg] = cn_s[mrow];
        }
#pragma unroll
        for (int n = 0; n < 4; ++n) {
#pragma unroll
            for (int reg = 0; reg < 16; ++reg) {
                // ascending code order within half -> strict < keeps first-min
                int mrow = 32 * mt + (reg & 3) + 8 * (reg >> 2) + 4 * half_id;
                int code = nb + mrow;
                float s = fmaf(acc[mt][n][reg], ACC_SCALE, cnreg[reg]);
                if (s < best[n]) { best[n] = s; bi[n] = code; }
            }
        }
    }

    // cross-half combine + XCD-local packed atomicMin
#pragma unroll
    for (int n = 0; n < 4; ++n) {
        float ob = __shfl_xor(best[n], 32, 64);
        int oi = __shfl_xor(bi[n], 32, 64);
        if (ob < best[n] || (ob == best[n] && oi < bi[n])) { best[n] = ob; bi[n] = oi; }
        if ((n >> 1) == half_id) {
            int tok = mb + w * 128 + n * 32 + (lane & 31);
            // monotone total-order encode of f32 (s' may be negative):
            // >=0: u^0x80000000 ; <0: u^0xFFFFFFFF. Equal s' -> equal key ->
            // min picks smaller code in low bits (first-min ties preserved).
            unsigned ub = __float_as_uint(best[n]);
            unsigned key = ub ^ ((unsigned)(((int)ub) >> 31) | 0x80000000u);
            ull pk = ((ull)key << 32) | (unsigned)bi[n];
            atomicMin(&packed[tok], pk);
        }
    }
}

// ---------------- zq: unpack winner, reconstruct code row, out + counts + loss
__global__ __launch_bounds__(256) void zq_kernel(const float* __restrict__ Z,
                                                 const char* __restrict__ Cpack,
                                                 const ull* __restrict__ packed,
                                                 float* __restrict__ out,
                                                 int* __restrict__ counts,
                                                 float* __restrict__ lpart) {
    int gid = blockIdx.x * 256 + threadIdx.x;   // over T*D/4 float4s
    int t = gid >> 5;                           // 32 float4 per token
    int d4 = gid & 31;
    int idx = (int)(packed[t] & 0xFFFFFFFFull);
    if (d4 == 0) atomicAdd(&counts[idx], 1);

    // reconstruct c[d0..d0+3] = (ch + cm) * 2^-12 (exact sum: spans < 24 bits)
    int d0 = 4 * d4;
    int kc = d0 >> 4, hf = (d0 >> 3) & 1, j0 = d0 & 7;
    const char* cp = Cpack + (size_t)(idx >> 6) * 32768
                   + (size_t)((((idx >> 5) & 1) * 8 + kc) * 1024
                              + (hf * 32 + (idx & 31)) * 16 + j0 * 2);
    v4h h = *(const v4h*)(cp);
    v4h m = *(const v4h*)(cp + 16384);
    float4 cv;
    cv.x = ((float)h[0] + (float)m[0]) * DESCALE;
    cv.y = ((float)h[1] + (float)m[1]) * DESCALE;
    cv.z = ((float)h[2] + (float)m[2]) * DESCALE;
    cv.w = ((float)h[3] + (float)m[3]) * DESCALE;

    float4 zv = ((const float4*)Z)[gid];
    float dx = cv.x - zv.x, dy = cv.y - zv.y, dz = cv.z - zv.z, dw = cv.w - zv.w;
    float4 o;
    o.x = zv.x + dx;    // z + (z_q - z): match reference elementwise rounding
    o.y = zv.y + dy;
    o.z = zv.z + dz;
    o.w = zv.w + dw;
    ((float4*)out)[gid] = o;

    float ls = dx * dx + dy * dy + dz * dz + dw * dw;
#pragma unroll
    for (int off = 32; off > 0; off >>= 1) ls += __shfl_down(ls, off, 64);
    __shared__ float red[4];
    int lane = threadIdx.x & 63, w = threadIdx.x >> 6;
    if (lane == 0) red[w] = ls;
    __syncthreads();
    // per-block partial store: no same-address atomic serialization
    if (threadIdx.x == 0) lpart[blockIdx.x] = (red[0] + red[1]) + (red[2] + red[3]);
}

// ---------------- scalars: commit_loss (from partials), perplexity ----------
__global__ __launch_bounds__(256) void scalars_kernel(const int* __restrict__ counts,
                                                      const float* __restrict__ lpart,
                                                      float* __restrict__ out) {
    float s = 0.f;
    for (int i = threadIdx.x; i < K_CODE; i += 256) {
        float e = (float)counts[i] * (1.0f / (float)T_TOK);
        s += e * logf(e + 1e-8f);
    }
    float ls = 0.f;
    for (int i = threadIdx.x; i < 4096; i += 256) ls += lpart[i];
#pragma unroll
    for (int off = 32; off > 0; off >>= 1) {
        s += __shfl_down(s, off, 64);
        ls += __shfl_down(ls, off, 64);
    }
    __shared__ float red[8];
    int lane = threadIdx.x & 63, w = threadIdx.x >> 6;
    if (lane == 0) { red[w] = s; red[4 + w] = ls; }
    __syncthreads();
    if (threadIdx.x == 0) {
        float ssum = (red[0] + red[1]) + (red[2] + red[3]);
        float lsum = (red[4] + red[5]) + (red[6] + red[7]);
        out[(size_t)T_TOK * D_DIM + 0] = 1.25f * lsum / (float)((size_t)T_TOK * D_DIM);
        out[(size_t)T_TOK * D_DIM + 1] = expf(-ssum);
    }
}

extern "C" void kernel_launch(void* const* d_in, const int* in_sizes, int n_in,
                              void* d_out, int out_size, void* d_ws, size_t ws_size,
                              hipStream_t stream) {
    const float* z   = (const float*)d_in[0];   // [8,4096,128]
    const float* emb = (const float*)d_in[1];   // [8192,128]
    const float* pw  = (const float*)d_in[2];   // [128,128]
    const float* pb  = (const float*)d_in[3];   // [128]
    float* out = (float*)d_out;

    // Zpack (f16 split fragments, 16.78 MB) lives in d_out: dead scratch until
    // zq_kernel overwrites d_out with the final z_q_st.
    char* Zpack = (char*)d_out;

    char* ws = (char*)d_ws;
    // layout (bytes):
    //   Cpack:  0        .. 4194304   (128 cb x 32768)
    //   cn:     4194304  .. 4227072   (8192 f32)
    //   lpart:  4227072  .. 4243456   (4096 f32)
    //   packed: 4358144  .. 4620288   (32768 u64)
    //   counts: 4620288  .. 4653056   (8192 i32)
    char*  Cpack  = ws + 0;
    float* cn     = (float*)(ws + 4194304);
    float* lpart  = (float*)(ws + 4227072);
    ull*   packed = (ull*)  (ws + 4358144);
    int*   counts = (int*)  (ws + 4620288);

    proj_kernel<<<K_CODE / 4, 256, 0, stream>>>(emb, pw, pb, Cpack, cn);
    prep_z_kernel<<<T_TOK / 32, 256, 0, stream>>>(z, Zpack, packed, counts);
    argmin_kernel<<<dim3(K_CODE / BN, T_TOK / BM), 512, 0, stream>>>(Zpack, Cpack, cn, packed);
    zq_kernel<<<(T_TOK * D_DIM / 4) / 256, 256, 0, stream>>>(z, Cpack, packed, out, counts, lpart);
    scalars_kernel<<<1, 256, 0, stream>>>(counts, lpart, out);
}

// Round 4
// 370.661 us; speedup vs baseline: 1.8217x; 1.0142x over previous
//
#include <hip/hip_runtime.h>
#include <math.h>

#define T_TOK 32768
#define D_DIM 128
#define K_CODE 8192
#define BM 256              // tokens per block (argmin): 4 waves x 64
#define BN 64               // codes per block (argmin)

typedef unsigned long long ull;
typedef _Float16 v8h __attribute__((ext_vector_type(8)));
typedef _Float16 v4h __attribute__((ext_vector_type(4)));
typedef float v16f __attribute__((ext_vector_type(16)));

#define SCALE 4096.0f        // 2^12: pushes f16 split residuals into normal range
#define DESCALE (1.0f / 4096.0f)
#define ACC_SCALE (-0x1p-23f)   // s' = cn - 2*dot (zn dropped: token-constant)

// Cpack layout (bytes): [cb=code/64][ (s*2+mt)*8+kc ][lane64][j8 f16]
// Zpack layout (bytes): [tb=token/32][ s ][ kc ][lane64][j8 f16]

// ---------------- proj: codebook row -> f16 split packs + cn ----------------
__global__ __launch_bounds__(256) void proj_kernel(const float* __restrict__ E,
                                                  const float* __restrict__ W,
                                                  const float* __restrict__ b,
                                                  char* __restrict__ Cpack,
                                                  float* __restrict__ cn) {
    int r = blockIdx.x * 4 + (threadIdx.x >> 6);
    int l = threadIdx.x & 63;          // 0..63
    const float4* E4 = (const float4*)(E + (size_t)r * D_DIM);
    const float4* WA = (const float4*)(W + (size_t)l * D_DIM);
    const float4* WB = (const float4*)(W + (size_t)(l + 64) * D_DIM);

    float4 aA = make_float4(0.f, 0.f, 0.f, 0.f);
    float4 aB = make_float4(0.f, 0.f, 0.f, 0.f);
#pragma unroll
    for (int dd = 0; dd < 32; ++dd) {
        float4 e = E4[dd];
        float4 wa = WA[dd], wb = WB[dd];
        aA.x = fmaf(e.x, wa.x, aA.x);
        aA.y = fmaf(e.y, wa.y, aA.y);
        aA.z = fmaf(e.z, wa.z, aA.z);
        aA.w = fmaf(e.w, wa.w, aA.w);
        aB.x = fmaf(e.x, wb.x, aB.x);
        aB.y = fmaf(e.y, wb.y, aB.y);
        aB.z = fmaf(e.z, wb.z, aB.z);
        aB.w = fmaf(e.w, wb.w, aB.w);
    }
    float vA = ((aA.x + aA.y) + (aA.z + aA.w)) + b[l];
    float vB = ((aB.x + aB.y) + (aB.z + aB.w)) + b[l + 64];

    char* cp = Cpack + (size_t)(r >> 6) * 32768;
    int mt = (r >> 5) & 1, rs = r & 31;
    {   // d = l
        int kc = l >> 4, hf = (l >> 3) & 1, j = l & 7;
        float f = vA * SCALE;
        _Float16 h = (_Float16)f;
        _Float16 m = (_Float16)(f - (float)h);
        size_t off = (size_t)((mt * 8 + kc) * 1024 + (hf * 32 + rs) * 16 + j * 2);
        *(_Float16*)(cp + off) = h;
        *(_Float16*)(cp + off + 16384) = m;
    }
    {   // d = l + 64
        int d = l + 64;
        int kc = d >> 4, hf = (d >> 3) & 1, j = d & 7;
        float f = vB * SCALE;
        _Float16 h = (_Float16)f;
        _Float16 m = (_Float16)(f - (float)h);
        size_t off = (size_t)((mt * 8 + kc) * 1024 + (hf * 32 + rs) * 16 + j * 2);
        *(_Float16*)(cp + off) = h;
        *(_Float16*)(cp + off + 16384) = m;
    }

    float s = vA * vA + vB * vB;
#pragma unroll
    for (int off = 32; off > 0; off >>= 1) s += __shfl_down(s, off, 64);
    if (l == 0) cn[r] = s;
}

// ---------------- prep_z: z -> f16 split packs + fused inits ----------------
__global__ __launch_bounds__(256) void prep_z_kernel(const float* __restrict__ Z,
                                                     char* __restrict__ Zpack,
                                                     ull* __restrict__ packed,
                                                     int* __restrict__ counts) {
    int tb = blockIdx.x;          // 32-token group
    int tid = threadIdx.x;
    int lane = tid & 63;
    int w = tid >> 6;

    // fused inits (zn kernel removed entirely: argmin no longer needs |z|^2)
    int g = blockIdx.x * 256 + tid;
    if (g < T_TOK) packed[g] = ~0ull;
    if (g < K_CODE) counts[g] = 0;

    char* zp = Zpack + (size_t)tb * 16384;
#pragma unroll
    for (int kq = 0; kq < 2; ++kq) {
        int kc = 2 * w + kq;
        const float* src = Z + (size_t)(tb * 32 + (lane & 31)) * D_DIM
                             + kc * 16 + (lane >> 5) * 8;
        float4 a = *(const float4*)(src);
        float4 c = *(const float4*)(src + 4);
        float vals[8] = {a.x, a.y, a.z, a.w, c.x, c.y, c.z, c.w};
        v8h h, m;
#pragma unroll
        for (int j = 0; j < 8; ++j) {
            float f = vals[j] * SCALE;
            _Float16 hh = (_Float16)f;
            h[j] = hh;
            m[j] = (_Float16)(f - (float)hh);
        }
        *(v8h*)(zp + (size_t)(kc * 1024 + lane * 16)) = h;
        *(v8h*)(zp + (size_t)(8192 + kc * 1024 + lane * 16)) = m;
    }
}

// ---------------- MFMA argmin: 3 independent 4-wave blocks per CU -----------
// R13 post-mortem: R3's 512-thread block at 244 unified regs (116 V + 128 A)
// = 2 waves/SIMD = ONE resident block/CU -> its stage/barrier/epilogue phases
// fully exposed, MfmaUtil stuck at 44% (pipe busy 97us ~= the f16 MFMA floor;
// only concurrency missing). R0 evidence: two INDEPENDENT blocks beat one
// barrier-locked one. Fix: shrink per-wave tile n=4 -> n=2 (acc 128->64 AGPR,
// pb 64->32 VGPR, ~150 total) so THREE independent 256-thread blocks fit per
// CU (launch_bounds(256,3) caps regs at 170; LDS 3x33KB=99KB). Staggered
// phases: one block's epilogue/stage overlaps the others' MFMA clusters.
// Total MFMA/epilogue/B-refill work conserved; stage traffic x4 but L2-hot
// (per-XCD: Cpack 4MB resident, one window swept at a time). Inner-loop
// arithmetic, swizzle, and tie-break semantics identical to R3.
__global__ __launch_bounds__(256, 3) void argmin_kernel(const char* __restrict__ Zpack,
                                                        const char* __restrict__ Cpack,
                                                        const float* __restrict__ cn,
                                                        ull* __restrict__ packed) {
    __shared__ __align__(16) char lds[33024];   // 32768 A-pack + 256 cn

    int tid = threadIdx.x;
    int lane = tid & 63;
    int w = __builtin_amdgcn_readfirstlane(tid >> 6);   // 0..3
    int half_id = lane >> 5;

    // XCD swizzle (bijective over 16384): bid%8 = XCD on MI355X.
    // XCD k sweeps cb 0..127 of window k, then window k+8, ... -> the
    // window's 128 KB Zpack slice is fetched once; Cpack cycles L2-resident.
    int bid = blockIdx.x;
    int xcd = bid & 7;
    int q = bid >> 3;
    int cb = q & 127;                  // code block (64 codes)
    int win = xcd + 8 * (q >> 7);      // token window (256 tokens)
    int nb = cb * BN;
    int mb = win * BM;

    // ---- one-time stage: A-pack via async global_load_lds (16B, linear) ----
    {
        const char* src = Cpack + (size_t)cb * 32768;
#pragma unroll
        for (int it = 0; it < 8; ++it) {
            int off = it * 4096 + tid * 16;
            __builtin_amdgcn_global_load_lds(
                (const __attribute__((address_space(1))) void*)(src + off),
                (__attribute__((address_space(3))) void*)(lds + off),
                16, 0, 0);
        }
        if (tid < 64) ((float*)(lds + 32768))[tid] = cn[nb + tid];
    }

    int tbw = (mb >> 5) + 2 * w;       // wave w owns token groups tbw, tbw+1
    const char* zb0 = Zpack + (size_t)tbw * 16384 + lane * 16;

    // 2-deep register prefetch: pb[frag = n*2 + split][buf = kc&1]
    v8h pb[4][2];
#pragma unroll
    for (int n = 0; n < 2; ++n) {
        pb[2 * n + 0][0] = *(const v8h*)(zb0 + n * 16384);
        pb[2 * n + 1][0] = *(const v8h*)(zb0 + n * 16384 + 8192);
        pb[2 * n + 0][1] = *(const v8h*)(zb0 + n * 16384 + 1024);
        pb[2 * n + 1][1] = *(const v8h*)(zb0 + n * 16384 + 8192 + 1024);
    }

    __syncthreads();   // drains staging; LDS read-only after this

    const char* ab = lds + lane * 16;
    const float* cn_s = (const float*)(lds + 32768);

    v16f acc[2][2];               // [mt codes][n token-groups]
#pragma unroll
    for (int mt = 0; mt < 2; ++mt)
#pragma unroll
        for (int n = 0; n < 2; ++n) acc[mt][n] = (v16f)0.f;

#pragma unroll
    for (int kc = 0; kc < 8; ++kc) {
        int curb = kc & 1;
        v8h Bh[2], Bm[2];
#pragma unroll
        for (int n = 0; n < 2; ++n) { Bh[n] = pb[2 * n][curb]; Bm[n] = pb[2 * n + 1][curb]; }
        if (kc < 6) {   // refill this buffer with kc+2 before the MFMAs
#pragma unroll
            for (int n = 0; n < 2; ++n) {
                pb[2 * n + 0][curb] = *(const v8h*)(zb0 + n * 16384 + (kc + 2) * 1024);
                pb[2 * n + 1][curb] = *(const v8h*)(zb0 + n * 16384 + 8192 + (kc + 2) * 1024);
            }
        }
        v8h Ah0 = *(const v8h*)(ab + (0 * 8 + kc) * 1024);       // mt0 hi
        v8h Ah1 = *(const v8h*)(ab + (1 * 8 + kc) * 1024);       // mt1 hi
        v8h Am0 = *(const v8h*)(ab + (2 * 8 + kc) * 1024);       // mt0 lo
        v8h Am1 = *(const v8h*)(ab + (3 * 8 + kc) * 1024);       // mt1 lo

        // pass h*h (same-acc reuse distance = 4)
#pragma unroll
        for (int n = 0; n < 2; ++n)
            acc[0][n] = __builtin_amdgcn_mfma_f32_32x32x16_f16(Ah0, Bh[n], acc[0][n], 0, 0, 0);
#pragma unroll
        for (int n = 0; n < 2; ++n)
            acc[1][n] = __builtin_amdgcn_mfma_f32_32x32x16_f16(Ah1, Bh[n], acc[1][n], 0, 0, 0);
        // pass h*m
#pragma unroll
        for (int n = 0; n < 2; ++n)
            acc[0][n] = __builtin_amdgcn_mfma_f32_32x32x16_f16(Ah0, Bm[n], acc[0][n], 0, 0, 0);
#pragma unroll
        for (int n = 0; n < 2; ++n)
            acc[1][n] = __builtin_amdgcn_mfma_f32_32x32x16_f16(Ah1, Bm[n], acc[1][n], 0, 0, 0);
        // pass m*h
#pragma unroll
        for (int n = 0; n < 2; ++n)
            acc[0][n] = __builtin_amdgcn_mfma_f32_32x32x16_f16(Am0, Bh[n], acc[0][n], 0, 0, 0);
#pragma unroll
        for (int n = 0; n < 2; ++n)
            acc[1][n] = __builtin_amdgcn_mfma_f32_32x32x16_f16(Am1, Bh[n], acc[1][n], 0, 0, 0);
    }

    // ---- epilogue: in-lane argmin per token group (zn-free: s' = cn - 2dot,
    // token-constant zn cancels in every comparison) ----
    float best[2];
    int bi[2];
#pragma unroll
    for (int n = 0; n < 2; ++n) { best[n] = 3.4e38f; bi[n] = nb; }

#pragma unroll
    for (int mt = 0; mt < 2; ++mt) {
        float cnreg[16];
#pragma unroll
        for (int reg = 0; reg < 16; ++reg) {
            int mrow = 32 * mt + (reg & 3) + 8 * (reg >> 2) + 4 * half_id;
            cnreg[reg] = cn_s[mrow];
        }
#pragma unroll
        for (int n = 0; n < 2; ++n) {
#pragma unroll
            for (int reg = 0; reg < 16; ++reg) {
                // ascending code order within half -> strict < keeps first-min
                int mrow = 32 * mt + (reg & 3) + 8 * (reg >> 2) + 4 * half_id;
                int code = nb + mrow;
                float s = fmaf(acc[mt][n][reg], ACC_SCALE, cnreg[reg]);
                if (s < best[n]) { best[n] = s; bi[n] = code; }
            }
        }
    }

    // cross-half combine + XCD-local packed atomicMin
#pragma unroll
    for (int n = 0; n < 2; ++n) {
        float ob = __shfl_xor(best[n], 32, 64);
        int oi = __shfl_xor(bi[n], 32, 64);
        if (ob < best[n] || (ob == best[n] && oi < bi[n])) { best[n] = ob; bi[n] = oi; }
        if ((n & 1) == half_id) {
            int tok = mb + w * 64 + n * 32 + (lane & 31);
            // monotone total-order encode of f32 (s' may be negative):
            // >=0: u^0x80000000 ; <0: u^0xFFFFFFFF. Equal s' -> equal key ->
            // min picks smaller code in low bits (first-min ties preserved).
            unsigned ub = __float_as_uint(best[n]);
            unsigned key = ub ^ ((unsigned)(((int)ub) >> 31) | 0x80000000u);
            ull pk = ((ull)key << 32) | (unsigned)bi[n];
            atomicMin(&packed[tok], pk);
        }
    }
}

// ---------------- zq: unpack winner, reconstruct code row, out + counts + loss
__global__ __launch_bounds__(256) void zq_kernel(const float* __restrict__ Z,
                                                 const char* __restrict__ Cpack,
                                                 const ull* __restrict__ packed,
                                                 float* __restrict__ out,
                                                 int* __restrict__ counts,
                                                 float* __restrict__ lpart) {
    int gid = blockIdx.x * 256 + threadIdx.x;   // over T*D/4 float4s
    int t = gid >> 5;                           // 32 float4 per token
    int d4 = gid & 31;
    int idx = (int)(packed[t] & 0xFFFFFFFFull);
    if (d4 == 0) atomicAdd(&counts[idx], 1);

    // reconstruct c[d0..d0+3] = (ch + cm) * 2^-12 (exact sum: spans < 24 bits)
    int d0 = 4 * d4;
    int kc = d0 >> 4, hf = (d0 >> 3) & 1, j0 = d0 & 7;
    const char* cp = Cpack + (size_t)(idx >> 6) * 32768
                   + (size_t)((((idx >> 5) & 1) * 8 + kc) * 1024
                              + (hf * 32 + (idx & 31)) * 16 + j0 * 2);
    v4h h = *(const v4h*)(cp);
    v4h m = *(const v4h*)(cp + 16384);
    float4 cv;
    cv.x = ((float)h[0] + (float)m[0]) * DESCALE;
    cv.y = ((float)h[1] + (float)m[1]) * DESCALE;
    cv.z = ((float)h[2] + (float)m[2]) * DESCALE;
    cv.w = ((float)h[3] + (float)m[3]) * DESCALE;

    float4 zv = ((const float4*)Z)[gid];
    float dx = cv.x - zv.x, dy = cv.y - zv.y, dz = cv.z - zv.z, dw = cv.w - zv.w;
    float4 o;
    o.x = zv.x + dx;    // z + (z_q - z): match reference elementwise rounding
    o.y = zv.y + dy;
    o.z = zv.z + dz;
    o.w = zv.w + dw;
    ((float4*)out)[gid] = o;

    float ls = dx * dx + dy * dy + dz * dz + dw * dw;
#pragma unroll
    for (int off = 32; off > 0; off >>= 1) ls += __shfl_down(ls, off, 64);
    __shared__ float red[4];
    int lane = threadIdx.x & 63, w = threadIdx.x >> 6;
    if (lane == 0) red[w] = ls;
    __syncthreads();
    // per-block partial store: no same-address atomic serialization
    if (threadIdx.x == 0) lpart[blockIdx.x] = (red[0] + red[1]) + (red[2] + red[3]);
}

// ---------------- scalars: commit_loss (from partials), perplexity ----------
__global__ __launch_bounds__(256) void scalars_kernel(const int* __restrict__ counts,
                                                      const float* __restrict__ lpart,
                                                      float* __restrict__ out) {
    float s = 0.f;
    for (int i = threadIdx.x; i < K_CODE; i += 256) {
        float e = (float)counts[i] * (1.0f / (float)T_TOK);
        s += e * logf(e + 1e-8f);
    }
    float ls = 0.f;
    for (int i = threadIdx.x; i < 4096; i += 256) ls += lpart[i];
#pragma unroll
    for (int off = 32; off > 0; off >>= 1) {
        s += __shfl_down(s, off, 64);
        ls += __shfl_down(ls, off, 64);
    }
    __shared__ float red[8];
    int lane = threadIdx.x & 63, w = threadIdx.x >> 6;
    if (lane == 0) { red[w] = s; red[4 + w] = ls; }
    __syncthreads();
    if (threadIdx.x == 0) {
        float ssum = (red[0] + red[1]) + (red[2] + red[3]);
        float lsum = (red[4] + red[5]) + (red[6] + red[7]);
        out[(size_t)T_TOK * D_DIM + 0] = 1.25f * lsum / (float)((size_t)T_TOK * D_DIM);
        out[(size_t)T_TOK * D_DIM + 1] = expf(-ssum);
    }
}

extern "C" void kernel_launch(void* const* d_in, const int* in_sizes, int n_in,
                              void* d_out, int out_size, void* d_ws, size_t ws_size,
                              hipStream_t stream) {
    const float* z   = (const float*)d_in[0];   // [8,4096,128]
    const float* emb = (const float*)d_in[1];   // [8192,128]
    const float* pw  = (const float*)d_in[2];   // [128,128]
    const float* pb  = (const float*)d_in[3];   // [128]
    float* out = (float*)d_out;

    // Zpack (f16 split fragments, 16.78 MB) lives in d_out: dead scratch until
    // zq_kernel overwrites d_out with the final z_q_st.
    char* Zpack = (char*)d_out;

    char* ws = (char*)d_ws;
    // layout (bytes):
    //   Cpack:  0        .. 4194304   (128 cb x 32768)
    //   cn:     4194304  .. 4227072   (8192 f32)
    //   lpart:  4227072  .. 4243456   (4096 f32)
    //   packed: 4358144  .. 4620288   (32768 u64)
    //   counts: 4620288  .. 4653056   (8192 i32)
    char*  Cpack  = ws + 0;
    float* cn     = (float*)(ws + 4194304);
    float* lpart  = (float*)(ws + 4227072);
    ull*   packed = (ull*)  (ws + 4358144);
    int*   counts = (int*)  (ws + 4620288);

    proj_kernel<<<K_CODE / 4, 256, 0, stream>>>(emb, pw, pb, Cpack, cn);
    prep_z_kernel<<<T_TOK / 32, 256, 0, stream>>>(z, Zpack, packed, counts);
    argmin_kernel<<<(K_CODE / BN) * (T_TOK / BM), 256, 0, stream>>>(Zpack, Cpack, cn, packed);
    zq_kernel<<<(T_TOK * D_DIM / 4) / 256, 256, 0, stream>>>(z, Cpack, packed, out, counts, lpart);
    scalars_kernel<<<1, 256, 0, stream>>>(counts, lpart, out);
}